// Round 4
// baseline (737.754 us; speedup 1.0000x reference)
//
#include <hip/hip_runtime.h>
#include <math.h>

// Problem constants
#define BB 4
#define TT 2048
#define DD 1024
#define HH 16
#define QKD 64
#define MM (BB*TT)          // 8192
#define NN 1024             // H*QK == D
#define KK 1024

typedef unsigned short u16;
typedef __attribute__((ext_vector_type(8))) short short8;   // 8 bf16 = 4 VGPRs
typedef __attribute__((ext_vector_type(4))) float float4v;  // MFMA C/D

// fp32 -> bf16 round-to-nearest-even
__device__ __forceinline__ u16 f2bf(float f) {
    union { float f; unsigned u; } v; v.f = f;
    unsigned r = (v.u + 0x7FFFu + ((v.u >> 16) & 1u)) >> 16;
    return (u16)r;
}

// async global->LDS, 16B per lane; LDS dest = wave-uniform base + lane*16
typedef __attribute__((address_space(3))) unsigned lds_u32_t;
typedef __attribute__((address_space(1))) const unsigned glb_u32_t;
__device__ __forceinline__ void gl2lds16(const u16* g, u16* l) {
    __builtin_amdgcn_global_load_lds((glb_u32_t*)g, (lds_u32_t*)l, 16, 0, 0);
}

// ---------------------------------------------------------------------------
// fp32 -> bf16 cast for activations (q, kv)
// ---------------------------------------------------------------------------
__global__ __launch_bounds__(256) void acast_kernel(
    const float* __restrict__ a, const float* __restrict__ b,
    u16* __restrict__ da, u16* __restrict__ db)
{
    const float* s = blockIdx.y ? b : a;
    u16* d = blockIdx.y ? db : da;
    size_t i = ((size_t)blockIdx.x * 256 + threadIdx.x) * 4;
    float4 v = *(const float4*)&s[i];
    ushort4 o = { f2bf(v.x), f2bf(v.y), f2bf(v.z), f2bf(v.w) };
    *(ushort4*)&d[i] = o;
}

// ---------------------------------------------------------------------------
// Weight transpose + cast: W[K][N] fp32 -> Wt[N][K] bf16, z selects matrix
// ---------------------------------------------------------------------------
__global__ __launch_bounds__(256) void wt_kernel(
    const float* __restrict__ Wq, const float* __restrict__ Wk,
    const float* __restrict__ Wv, const float* __restrict__ Wo,
    u16* __restrict__ dstbase)
{
    const int z = blockIdx.z;
    const float* src = (z == 0) ? Wq : (z == 1) ? Wk : (z == 2) ? Wv : Wo;
    u16* out = dstbase + (size_t)z * (KK * NN);
    const int bi = blockIdx.y, bj = blockIdx.x;
    __shared__ float tile[64][65];
    const int t = threadIdx.x;
    #pragma unroll
    for (int p = 0; p < 4; p++) {
        int idx = p * 256 + t;
        int r = idx >> 4, c4 = (idx & 15) << 2;
        float4 v = *(const float4*)&src[(size_t)(bi * 64 + r) * NN + bj * 64 + c4];
        tile[r][c4 + 0] = v.x; tile[r][c4 + 1] = v.y;
        tile[r][c4 + 2] = v.z; tile[r][c4 + 3] = v.w;
    }
    __syncthreads();
    #pragma unroll
    for (int p = 0; p < 4; p++) {
        int idx = p * 256 + t;
        int rn = idx >> 4, c4 = (idx & 15) << 2;
        ushort4 o = { f2bf(tile[c4 + 0][rn]), f2bf(tile[c4 + 1][rn]),
                      f2bf(tile[c4 + 2][rn]), f2bf(tile[c4 + 3][rn]) };
        *(ushort4*)&out[(size_t)(bj * 64 + rn) * KK + bi * 64 + c4] = o;
    }
}

// ---------------------------------------------------------------------------
// bf16 MFMA GEMM main loop (m97 structure). See round-3 notes.
// ---------------------------------------------------------------------------
__device__ __forceinline__ void gemm_mainloop(
    const u16* __restrict__ A, const u16* __restrict__ Bt,
    int m0, int n0, u16* As, u16* Bs, float4v (&acc)[4][4])
{
    const int tid = threadIdx.x;
    const int wave = tid >> 6, lane = tid & 63;
    const int l15 = lane & 15, lg = lane >> 4;
    const int wm = wave >> 1, wn = wave & 1;

    const int lr = lane >> 3;
    const int lc = lane & 7;

    for (int k0 = 0; k0 < KK; k0 += 64) {
        #pragma unroll
        for (int i = 0; i < 4; i++) {
            int chunk = wave * 4 + i;
            int row = chunk * 8 + lr;
            int gcb = lc ^ (row & 7);
            gl2lds16(A  + (size_t)(m0 + row) * KK + k0 + gcb * 8, As + chunk * 512);
            gl2lds16(Bt + (size_t)(n0 + row) * KK + k0 + gcb * 8, Bs + chunk * 512);
        }
        __syncthreads();

        short8 af[2][4], bf[2][4];
        #pragma unroll
        for (int kc = 0; kc < 2; kc++) {
            #pragma unroll
            for (int x = 0; x < 4; x++) {
                int ra = wm * 64 + x * 16 + l15;
                int sa = (kc * 4 + lg) ^ (ra & 7);
                af[kc][x] = *(const short8*)(As + ra * 64 + sa * 8);
                int rb = wn * 64 + x * 16 + l15;
                int sb = (kc * 4 + lg) ^ (rb & 7);
                bf[kc][x] = *(const short8*)(Bs + rb * 64 + sb * 8);
            }
        }
        #pragma unroll
        for (int mi = 0; mi < 4; mi++)
            #pragma unroll
            for (int nj = 0; nj < 4; nj++) {
                acc[mi][nj] = __builtin_amdgcn_mfma_f32_16x16x32_bf16(af[0][mi], bf[0][nj], acc[mi][nj], 0, 0, 0);
                acc[mi][nj] = __builtin_amdgcn_mfma_f32_16x16x32_bf16(af[1][mi], bf[1][nj], acc[mi][nj], 0, 0, 0);
            }
        __syncthreads();
    }
}

// ---------------------------------------------------------------------------
// QKV projection GEMM, z in {0:Q, 1:K, 2:V}. Epilogue fuses bias + RMSNorm +
// RoPE (Q,K) and writes bf16. Q,K -> (B,H,T,QK); V -> transposed (B,H,QK,T)
// so attention can stage V^T with vectorized loads.
// ---------------------------------------------------------------------------
__global__ __launch_bounds__(256) void qkv_gemm(
    const u16* __restrict__ qb, const u16* __restrict__ kvb,
    const u16* __restrict__ Wt,
    const float* __restrict__ bq, const float* __restrict__ bk, const float* __restrict__ bv,
    const int* __restrict__ qpos, const int* __restrict__ kpos,
    const float* __restrict__ q_scale, const float* __restrict__ k_scale,
    u16* __restrict__ qh, u16* __restrict__ kh, u16* __restrict__ vt)
{
    __shared__ u16 As[128 * 64];
    __shared__ u16 Bs[128 * 64];

    const int z = blockIdx.z;
    const u16* A        = (z == 0) ? qb : kvb;
    const u16* B        = Wt + (size_t)z * (KK * NN);
    const float* bias   = (z == 0) ? bq : (z == 1) ? bk : bv;
    const float* scl    = (z == 0) ? q_scale : k_scale;
    const int* pos_arr  = (z == 0) ? qpos : kpos;

    const int m0 = blockIdx.y * 128, n0 = blockIdx.x * 128;

    float4v acc[4][4];
    #pragma unroll
    for (int i = 0; i < 4; i++)
        #pragma unroll
        for (int j = 0; j < 4; j++) acc[i][j] = (float4v){0.f, 0.f, 0.f, 0.f};

    gemm_mainloop(A, B, m0, n0, As, Bs, acc);

    const int lane = threadIdx.x & 63, wave = threadIdx.x >> 6;
    const int l15 = lane & 15, lg = lane >> 4;
    const int wm = wave >> 1, wn = wave & 1;
    const int mbase = m0 + wm * 64;
    const int nbase = n0 + wn * 64;
    const int h = nbase >> 6;

    float bia[4], sc[4];
    #pragma unroll
    for (int nj = 0; nj < 4; nj++) {
        bia[nj] = bias[h * 64 + nj * 16 + l15];
        sc[nj]  = 1.0f + scl[nj * 16 + l15];
    }
    float invts[2];
    #pragma unroll
    for (int p = 0; p < 2; p++)
        invts[p] = powf(10000.0f, -(float)(p * 16 + l15) * (1.0f / 32.0f));

    const float QMUL = 0.125f * 1.44269504088896340736f;

    #pragma unroll
    for (int mi = 0; mi < 4; mi++) {
        #pragma unroll
        for (int r = 0; r < 4; r++) {
            const int m = mbase + mi * 16 + lg * 4 + r;
            const int b = m >> 11, t = m & 2047;
            float v[4];
            #pragma unroll
            for (int nj = 0; nj < 4; nj++) v[nj] = acc[mi][nj][r] + bia[nj];

            if (z < 2) {
                float ss = v[0]*v[0] + v[1]*v[1] + v[2]*v[2] + v[3]*v[3];
                ss += __shfl_xor(ss, 1);
                ss += __shfl_xor(ss, 2);
                ss += __shfl_xor(ss, 4);
                ss += __shfl_xor(ss, 8);
                float rn = rsqrtf(ss * (1.0f / 64.0f) + 1e-6f);
                #pragma unroll
                for (int nj = 0; nj < 4; nj++) v[nj] = v[nj] * rn * sc[nj];

                const float pos = (float)pos_arr[b * TT + t];
                #pragma unroll
                for (int p = 0; p < 2; p++) {
                    float ang = pos * invts[p];
                    float s = sinf(ang), c = cosf(ang);
                    float x1 = v[p], x2 = v[p + 2];
                    v[p]     = x1 * c - x2 * s;
                    v[p + 2] = x2 * c + x1 * s;
                }
                if (z == 0) {
                    #pragma unroll
                    for (int nj = 0; nj < 4; nj++) v[nj] *= QMUL;
                }
                u16* op = ((z == 0) ? qh : kh)
                          + ((size_t)((b * HH + h) * TT + t)) * QKD + l15;
                #pragma unroll
                for (int nj = 0; nj < 4; nj++) op[nj * 16] = f2bf(v[nj]);
            } else {
                // V transposed: vt[((b*H+h)*QKD + c) * TT + t]
                #pragma unroll
                for (int nj = 0; nj < 4; nj++)
                    vt[((size_t)(b * HH + h) * QKD + nj * 16 + l15) * TT + t] = f2bf(v[nj]);
            }
        }
    }
}

// ---------------------------------------------------------------------------
// Output projection GEMM: attn_b[M,K] bf16 @ Wo_t[N,K]^T + bo -> out fp32
// ---------------------------------------------------------------------------
__global__ __launch_bounds__(256) void out_gemm(
    const u16* __restrict__ A, const u16* __restrict__ Bt,
    const float* __restrict__ bo, float* __restrict__ out)
{
    __shared__ u16 As[128 * 64];
    __shared__ u16 Bs[128 * 64];

    const int m0 = blockIdx.y * 128, n0 = blockIdx.x * 128;

    float4v acc[4][4];
    #pragma unroll
    for (int i = 0; i < 4; i++)
        #pragma unroll
        for (int j = 0; j < 4; j++) acc[i][j] = (float4v){0.f, 0.f, 0.f, 0.f};

    gemm_mainloop(A, Bt, m0, n0, As, Bs, acc);

    const int lane = threadIdx.x & 63, wave = threadIdx.x >> 6;
    const int l15 = lane & 15, lg = lane >> 4;
    const int wm = wave >> 1, wn = wave & 1;
    const int mbase = m0 + wm * 64;
    const int nbase = n0 + wn * 64;

    float bov[4];
    #pragma unroll
    for (int nj = 0; nj < 4; nj++) bov[nj] = bo[nbase + nj * 16 + l15];

    #pragma unroll
    for (int mi = 0; mi < 4; mi++)
        #pragma unroll
        for (int r = 0; r < 4; r++) {
            const int m = mbase + mi * 16 + lg * 4 + r;
            float* op = out + (size_t)m * NN + nbase + l15;
            #pragma unroll
            for (int nj = 0; nj < 4; nj++)
                op[nj * 16] = acc[mi][nj][r] + bov[nj];
        }
}

// ---------------------------------------------------------------------------
// MFMA flash attention, causal, PAIRED Q-tiles for uniform work.
// Block = pair (qtL=i, qtH=31-i) of 64-query tiles for one (b,h):
// every block runs exactly 33 stream-iterations. Grid = 16*H*B = 1024 blocks
// = 4/CU with launch_bounds(256,4): all blocks resident, no ragged tail.
// V comes in pre-transposed (B,H,QK,T) so both K and V stage with b128s.
// ---------------------------------------------------------------------------
#define LSTR 72

__global__ __launch_bounds__(256, 4) void attn_mfma(
    const u16* __restrict__ qh, const u16* __restrict__ kh,
    const u16* __restrict__ vt, const float* __restrict__ head_scale,
    u16* __restrict__ out)
{
    __shared__ u16 Ks[64 * LSTR];      // K tile [key][d]
    __shared__ u16 Vs[64 * LSTR];      // V^T tile [d][key]
    __shared__ u16 Ps[4][16 * LSTR];   // per-wave P round-trip [q][key]

    const int b = blockIdx.z, h = blockIdx.y, pi = blockIdx.x;   // pi 0..15
    const int t0L = pi * 64, t0H = (31 - pi) * 64;
    const int tid  = threadIdx.x;
    const int wave = tid >> 6, lane = tid & 63;
    const int l15 = lane & 15, lg = lane >> 4;

    const size_t bh_off = (size_t)(b * HH + h) * TT * QKD;
    const u16* qbh = qh + bh_off;
    const u16* kbh = kh + bh_off;
    const u16* vtb = vt + bh_off;      // [d][t], d rows of length TT

    // Q fragments for both tiles (A: m=lane&15, k=lg*8+j)
    short8 qfL[2], qfH[2];
    #pragma unroll
    for (int kc = 0; kc < 2; kc++) {
        qfL[kc] = *(const short8*)(qbh + (size_t)(t0L + wave * 16 + l15) * QKD + kc * 32 + lg * 8);
        qfH[kc] = *(const short8*)(qbh + (size_t)(t0H + wave * 16 + l15) * QKD + kc * 32 + lg * 8);
    }

    float4v oL[4], oH[4];
    #pragma unroll
    for (int nt = 0; nt < 4; nt++) {
        oL[nt] = (float4v){0.f, 0.f, 0.f, 0.f};
        oH[nt] = (float4v){0.f, 0.f, 0.f, 0.f};
    }
    float mL[4] = {-INFINITY, -INFINITY, -INFINITY, -INFINITY};
    float mH[4] = {-INFINITY, -INFINITY, -INFINITY, -INFINITY};
    float lL[4] = {0.f, 0.f, 0.f, 0.f};
    float lH[4] = {0.f, 0.f, 0.f, 0.f};

    u16* pw = Ps[wave];

    // one online-softmax + PV step for one stream
    auto process = [&](const short8 (&qf)[2], float4v (&o_acc)[4],
                       float (&m_run)[4], float (&l_run)[4], int t0, int j0) {
        float4v sarr[4];
        #pragma unroll
        for (int nt = 0; nt < 4; nt++) {
            float4v s = (float4v){0.f, 0.f, 0.f, 0.f};
            #pragma unroll
            for (int kc = 0; kc < 2; kc++) {
                short8 bfrag = *(const short8*)&Ks[(nt * 16 + l15) * LSTR + kc * 32 + lg * 8];
                s = __builtin_amdgcn_mfma_f32_16x16x32_bf16(qf[kc], bfrag, s, 0, 0, 0);
            }
            sarr[nt] = s;
        }

        if (j0 == t0) {   // diagonal tile: causal mask
            const int qbase = t0 + wave * 16 + lg * 4;
            #pragma unroll
            for (int nt = 0; nt < 4; nt++) {
                int jkey = j0 + nt * 16 + l15;
                #pragma unroll
                for (int r = 0; r < 4; r++)
                    if (jkey > qbase + r) sarr[nt][r] = -INFINITY;
            }
        }

        float alpha[4], rowsum[4];
        #pragma unroll
        for (int r = 0; r < 4; r++) {
            float m = fmaxf(fmaxf(sarr[0][r], sarr[1][r]), fmaxf(sarr[2][r], sarr[3][r]));
            m = fmaxf(m, __shfl_xor(m, 1));
            m = fmaxf(m, __shfl_xor(m, 2));
            m = fmaxf(m, __shfl_xor(m, 4));
            m = fmaxf(m, __shfl_xor(m, 8));
            float m_new = fmaxf(m_run[r], m);
            alpha[r] = exp2f(m_run[r] - m_new);
            m_run[r] = m_new;
            rowsum[r] = 0.f;
        }
        #pragma unroll
        for (int nt = 0; nt < 4; nt++) {
            #pragma unroll
            for (int r = 0; r < 4; r++) {
                float p = exp2f(sarr[nt][r] - m_run[r]);
                rowsum[r] += p;
                pw[(lg * 4 + r) * LSTR + nt * 16 + l15] = f2bf(p);
            }
        }
        #pragma unroll
        for (int r = 0; r < 4; r++) {
            float rs = rowsum[r];
            rs += __shfl_xor(rs, 1);
            rs += __shfl_xor(rs, 2);
            rs += __shfl_xor(rs, 4);
            rs += __shfl_xor(rs, 8);
            l_run[r] = l_run[r] * alpha[r] + rs;
        }
        #pragma unroll
        for (int nt = 0; nt < 4; nt++)
            #pragma unroll
            for (int r = 0; r < 4; r++)
                o_acc[nt][r] *= alpha[r];

        short8 pf[2];
        #pragma unroll
        for (int kc = 0; kc < 2; kc++)
            pf[kc] = *(const short8*)&pw[l15 * LSTR + kc * 32 + lg * 8];
        #pragma unroll
        for (int nt = 0; nt < 4; nt++) {
            #pragma unroll
            for (int kc = 0; kc < 2; kc++) {
                short8 vfrag = *(const short8*)&Vs[(nt * 16 + l15) * LSTR + kc * 32 + lg * 8];
                o_acc[nt] = __builtin_amdgcn_mfma_f32_16x16x32_bf16(pf[kc], vfrag, o_acc[nt], 0, 0, 0);
            }
        }
    };

    for (int j0 = 0; j0 <= t0H; j0 += 64) {
        // stage K [key][d] and V^T [d][key], both vectorized
        #pragma unroll
        for (int r = 0; r < 2; r++) {
            int idx = r * 256 + tid;
            int row = idx >> 3, cb = (idx & 7) * 8;
            *(short8*)&Ks[row * LSTR + cb] =
                *(const short8*)(kbh + (size_t)(j0 + row) * QKD + cb);
            *(short8*)&Vs[row * LSTR + cb] =
                *(const short8*)(vtb + (size_t)row * TT + j0 + cb);
        }
        __syncthreads();

        process(qfH, oH, mH, lH, t0H, j0);
        if (j0 <= t0L) process(qfL, oL, mL, lL, t0L, j0);
        __syncthreads();
    }

    // epilogue: /l, *(1+head_scale), write (B,T,H*QK) bf16 — both tiles
    const float hs = 1.0f + head_scale[h];
    #pragma unroll
    for (int r = 0; r < 4; r++) {
        {
            const int q = t0L + wave * 16 + lg * 4 + r;
            const float f = hs / lL[r];
            u16* op = out + ((size_t)(b * TT + q) * NN) + h * QKD + l15;
            #pragma unroll
            for (int nt = 0; nt < 4; nt++) op[nt * 16] = f2bf(oL[nt][r] * f);
        }
        {
            const int q = t0H + wave * 16 + lg * 4 + r;
            const float f = hs / lH[r];
            u16* op = out + ((size_t)(b * TT + q) * NN) + h * QKD + l15;
            #pragma unroll
            for (int nt = 0; nt < 4; nt++) op[nt * 16] = f2bf(oH[nt][r] * f);
        }
    }
}

// ---------------------------------------------------------------------------
extern "C" void kernel_launch(void* const* d_in, const int* in_sizes, int n_in,
                              void* d_out, int out_size, void* d_ws, size_t ws_size,
                              hipStream_t stream)
{
    const float* q          = (const float*)d_in[0];
    const float* kv         = (const float*)d_in[1];
    /* d_in[2] = causal mask -- handled analytically */
    const int*   qpos       = (const int*)d_in[3];
    const int*   kpos       = (const int*)d_in[4];
    const float* Wq         = (const float*)d_in[5];
    const float* bq         = (const float*)d_in[6];
    const float* Wk         = (const float*)d_in[7];
    const float* bk         = (const float*)d_in[8];
    const float* Wv         = (const float*)d_in[9];
    const float* bv         = (const float*)d_in[10];
    const float* q_scale    = (const float*)d_in[11];
    const float* k_scale    = (const float*)d_in[12];
    const float* head_scale = (const float*)d_in[13];
    const float* Wo         = (const float*)d_in[14];
    const float* bo         = (const float*)d_in[15];
    float* out = (float*)d_out;

    // workspace layout (bytes):
    //   [  0 MB, 16 MB)  qb     (M,K) bf16
    //   [ 16 MB, 32 MB)  kvb    (M,K) bf16
    //   [ 32 MB, 40 MB)  Wt     4 x (N,K) bf16 transposed: Wq,Wk,Wv,Wo
    //   [ 40 MB, 56 MB)  qh_b   (B,H,T,QK) bf16
    //   [ 56 MB, 72 MB)  kh_b   (B,H,T,QK) bf16
    //   [ 72 MB, 88 MB)  vt_b   (B,H,QK,T) bf16  -- V transposed
    //   [ 88 MB,104 MB)  attn_b (B,T,N) bf16
    char* ws = (char*)d_ws;
    u16* qb     = (u16*)(ws);
    u16* kvb    = (u16*)(ws + (16u << 20));
    u16* Wt     = (u16*)(ws + (32u << 20));
    u16* qh_b   = (u16*)(ws + (40u << 20));
    u16* kh_b   = (u16*)(ws + (56u << 20));
    u16* vt_b   = (u16*)(ws + (72u << 20));
    u16* attn_b = (u16*)(ws + (88u << 20));

    acast_kernel<<<dim3(MM * DD / (256 * 4), 2), 256, 0, stream>>>(q, kv, qb, kvb);
    wt_kernel<<<dim3(16, 16, 4), 256, 0, stream>>>(Wq, Wk, Wv, Wo, Wt);
    qkv_gemm<<<dim3(NN / 128, MM / 128, 3), 256, 0, stream>>>(
        qb, kvb, Wt, bq, bk, bv, qpos, kpos, q_scale, k_scale, qh_b, kh_b, vt_b);
    attn_mfma<<<dim3(16, HH, BB), 256, 0, stream>>>(qh_b, kh_b, vt_b, head_scale, attn_b);
    out_gemm<<<dim3(NN / 128, MM / 128), 256, 0, stream>>>(attn_b, Wt + (size_t)3 * KK * NN, bo, out);
}

// Round 6
// 707.297 us; speedup vs baseline: 1.0431x; 1.0431x over previous
//
#include <hip/hip_runtime.h>
#include <math.h>

// Problem constants
#define BB 4
#define TT 2048
#define DD 1024
#define HH 16
#define QKD 64
#define MM (BB*TT)          // 8192
#define NN 1024             // H*QK == D
#define KK 1024

typedef unsigned short u16;
typedef __attribute__((ext_vector_type(8))) short short8;   // 8 bf16 = 4 VGPRs
typedef __attribute__((ext_vector_type(4))) float float4v;  // MFMA C/D

// fp32 -> bf16 round-to-nearest-even
__device__ __forceinline__ u16 f2bf(float f) {
    union { float f; unsigned u; } v; v.f = f;
    unsigned r = (v.u + 0x7FFFu + ((v.u >> 16) & 1u)) >> 16;
    return (u16)r;
}

// async global->LDS, 16B per lane; LDS dest = wave-uniform base + lane*16
typedef __attribute__((address_space(3))) unsigned lds_u32_t;
typedef __attribute__((address_space(1))) const unsigned glb_u32_t;
__device__ __forceinline__ void gl2lds16(const u16* g, u16* l) {
    __builtin_amdgcn_global_load_lds((glb_u32_t*)g, (lds_u32_t*)l, 16, 0, 0);
}

// ---------------------------------------------------------------------------
// fp32 -> bf16 cast for activations (q, kv)
// ---------------------------------------------------------------------------
__global__ __launch_bounds__(256) void acast_kernel(
    const float* __restrict__ a, const float* __restrict__ b,
    u16* __restrict__ da, u16* __restrict__ db)
{
    const float* s = blockIdx.y ? b : a;
    u16* d = blockIdx.y ? db : da;
    size_t i = ((size_t)blockIdx.x * 256 + threadIdx.x) * 4;
    float4 v = *(const float4*)&s[i];
    ushort4 o = { f2bf(v.x), f2bf(v.y), f2bf(v.z), f2bf(v.w) };
    *(ushort4*)&d[i] = o;
}

// ---------------------------------------------------------------------------
// Weight transpose + cast: W[K][N] fp32 -> Wt[N][K] bf16, z selects matrix
// ---------------------------------------------------------------------------
__global__ __launch_bounds__(256) void wt_kernel(
    const float* __restrict__ Wq, const float* __restrict__ Wk,
    const float* __restrict__ Wv, const float* __restrict__ Wo,
    u16* __restrict__ dstbase)
{
    const int z = blockIdx.z;
    const float* src = (z == 0) ? Wq : (z == 1) ? Wk : (z == 2) ? Wv : Wo;
    u16* out = dstbase + (size_t)z * (KK * NN);
    const int bi = blockIdx.y, bj = blockIdx.x;
    __shared__ float tile[64][65];
    const int t = threadIdx.x;
    #pragma unroll
    for (int p = 0; p < 4; p++) {
        int idx = p * 256 + t;
        int r = idx >> 4, c4 = (idx & 15) << 2;
        float4 v = *(const float4*)&src[(size_t)(bi * 64 + r) * NN + bj * 64 + c4];
        tile[r][c4 + 0] = v.x; tile[r][c4 + 1] = v.y;
        tile[r][c4 + 2] = v.z; tile[r][c4 + 3] = v.w;
    }
    __syncthreads();
    #pragma unroll
    for (int p = 0; p < 4; p++) {
        int idx = p * 256 + t;
        int rn = idx >> 4, c4 = (idx & 15) << 2;
        ushort4 o = { f2bf(tile[c4 + 0][rn]), f2bf(tile[c4 + 1][rn]),
                      f2bf(tile[c4 + 2][rn]), f2bf(tile[c4 + 3][rn]) };
        *(ushort4*)&out[(size_t)(bj * 64 + rn) * KK + bi * 64 + c4] = o;
    }
}

// ---------------------------------------------------------------------------
// bf16 MFMA GEMM main loop (m97 structure). See round-3 notes.
// ---------------------------------------------------------------------------
__device__ __forceinline__ void gemm_mainloop(
    const u16* __restrict__ A, const u16* __restrict__ Bt,
    int m0, int n0, u16* As, u16* Bs, float4v (&acc)[4][4])
{
    const int tid = threadIdx.x;
    const int wave = tid >> 6, lane = tid & 63;
    const int l15 = lane & 15, lg = lane >> 4;
    const int wm = wave >> 1, wn = wave & 1;

    const int lr = lane >> 3;
    const int lc = lane & 7;

    for (int k0 = 0; k0 < KK; k0 += 64) {
        #pragma unroll
        for (int i = 0; i < 4; i++) {
            int chunk = wave * 4 + i;
            int row = chunk * 8 + lr;
            int gcb = lc ^ (row & 7);
            gl2lds16(A  + (size_t)(m0 + row) * KK + k0 + gcb * 8, As + chunk * 512);
            gl2lds16(Bt + (size_t)(n0 + row) * KK + k0 + gcb * 8, Bs + chunk * 512);
        }
        __syncthreads();

        short8 af[2][4], bf[2][4];
        #pragma unroll
        for (int kc = 0; kc < 2; kc++) {
            #pragma unroll
            for (int x = 0; x < 4; x++) {
                int ra = wm * 64 + x * 16 + l15;
                int sa = (kc * 4 + lg) ^ (ra & 7);
                af[kc][x] = *(const short8*)(As + ra * 64 + sa * 8);
                int rb = wn * 64 + x * 16 + l15;
                int sb = (kc * 4 + lg) ^ (rb & 7);
                bf[kc][x] = *(const short8*)(Bs + rb * 64 + sb * 8);
            }
        }
        #pragma unroll
        for (int mi = 0; mi < 4; mi++)
            #pragma unroll
            for (int nj = 0; nj < 4; nj++) {
                acc[mi][nj] = __builtin_amdgcn_mfma_f32_16x16x32_bf16(af[0][mi], bf[0][nj], acc[mi][nj], 0, 0, 0);
                acc[mi][nj] = __builtin_amdgcn_mfma_f32_16x16x32_bf16(af[1][mi], bf[1][nj], acc[mi][nj], 0, 0, 0);
            }
        __syncthreads();
    }
}

// ---------------------------------------------------------------------------
// QKV projection GEMM, z in {0:Q, 1:K, 2:V}. Epilogue fuses bias + RMSNorm +
// RoPE (Q,K) -> (B,H,T,QK) bf16. V -> (B,H,QK,T) bf16 via an LDS 128x128
// transpose so the global writes are contiguous 128B bursts.
// ---------------------------------------------------------------------------
#define TSTR 136   // u16 stride for the transpose buffer: 16B-aligned rows

__global__ __launch_bounds__(256) void qkv_gemm(
    const u16* __restrict__ qb, const u16* __restrict__ kvb,
    const u16* __restrict__ Wt,
    const float* __restrict__ bq, const float* __restrict__ bk, const float* __restrict__ bv,
    const int* __restrict__ qpos, const int* __restrict__ kpos,
    const float* __restrict__ q_scale, const float* __restrict__ k_scale,
    u16* __restrict__ qh, u16* __restrict__ kh, u16* __restrict__ vt)
{
    __shared__ u16 smem[128 * TSTR];   // 34816 B; mainloop uses first 32 KB
    u16* As = smem;
    u16* Bs = smem + 128 * 64;

    const int z = blockIdx.z;
    const u16* A        = (z == 0) ? qb : kvb;
    const u16* B        = Wt + (size_t)z * (KK * NN);
    const float* bias   = (z == 0) ? bq : (z == 1) ? bk : bv;
    const float* scl    = (z == 0) ? q_scale : k_scale;
    const int* pos_arr  = (z == 0) ? qpos : kpos;

    const int m0 = blockIdx.y * 128, n0 = blockIdx.x * 128;

    float4v acc[4][4];
    #pragma unroll
    for (int i = 0; i < 4; i++)
        #pragma unroll
        for (int j = 0; j < 4; j++) acc[i][j] = (float4v){0.f, 0.f, 0.f, 0.f};

    gemm_mainloop(A, B, m0, n0, As, Bs, acc);

    const int tid = threadIdx.x;
    const int lane = tid & 63, wave = tid >> 6;
    const int l15 = lane & 15, lg = lane >> 4;
    const int wm = wave >> 1, wn = wave & 1;
    const int mbase = m0 + wm * 64;
    const int nbase = n0 + wn * 64;
    const int h = nbase >> 6;

    float bia[4];
    #pragma unroll
    for (int nj = 0; nj < 4; nj++)
        bia[nj] = bias[h * 64 + nj * 16 + l15];

    if (z < 2) {
        float sc[4];
        #pragma unroll
        for (int nj = 0; nj < 4; nj++) sc[nj] = 1.0f + scl[nj * 16 + l15];
        float invts[2];
        #pragma unroll
        for (int p = 0; p < 2; p++)
            invts[p] = powf(10000.0f, -(float)(p * 16 + l15) * (1.0f / 32.0f));
        const float QMUL = 0.125f * 1.44269504088896340736f;

        #pragma unroll
        for (int mi = 0; mi < 4; mi++) {
            #pragma unroll
            for (int r = 0; r < 4; r++) {
                const int m = mbase + mi * 16 + lg * 4 + r;
                const int b = m >> 11, t = m & 2047;
                float v[4];
                #pragma unroll
                for (int nj = 0; nj < 4; nj++) v[nj] = acc[mi][nj][r] + bia[nj];

                float ss = v[0]*v[0] + v[1]*v[1] + v[2]*v[2] + v[3]*v[3];
                ss += __shfl_xor(ss, 1);
                ss += __shfl_xor(ss, 2);
                ss += __shfl_xor(ss, 4);
                ss += __shfl_xor(ss, 8);
                float rn = rsqrtf(ss * (1.0f / 64.0f) + 1e-6f);
                #pragma unroll
                for (int nj = 0; nj < 4; nj++) v[nj] = v[nj] * rn * sc[nj];

                const float pos = (float)pos_arr[b * TT + t];
                #pragma unroll
                for (int p = 0; p < 2; p++) {
                    float ang = pos * invts[p];
                    float s = sinf(ang), c = cosf(ang);
                    float x1 = v[p], x2 = v[p + 2];
                    v[p]     = x1 * c - x2 * s;
                    v[p + 2] = x2 * c + x1 * s;
                }
                if (z == 0) {
                    #pragma unroll
                    for (int nj = 0; nj < 4; nj++) v[nj] *= QMUL;
                }
                u16* op = ((z == 0) ? qh : kh)
                          + ((size_t)((b * HH + h) * TT + t)) * QKD + l15;
                #pragma unroll
                for (int nj = 0; nj < 4; nj++) op[nj * 16] = f2bf(v[nj]);
            }
        }
    } else {
        // V: LDS transpose [n_local][m_local], then coalesced V^T writes.
        // (mainloop's final __syncthreads makes smem safe to reuse)
        #pragma unroll
        for (int mi = 0; mi < 4; mi++) {
            const int m_loc = wm * 64 + mi * 16 + lg * 4;
            #pragma unroll
            for (int nj = 0; nj < 4; nj++) {
                const int n_loc = wn * 64 + nj * 16 + l15;
                ushort4 o = { f2bf(acc[mi][nj][0] + bia[nj]),
                              f2bf(acc[mi][nj][1] + bia[nj]),
                              f2bf(acc[mi][nj][2] + bia[nj]),
                              f2bf(acc[mi][nj][3] + bia[nj]) };
                *(ushort4*)&smem[n_loc * TSTR + m_loc] = o;
            }
        }
        __syncthreads();

        // 128 rows x 128 u16: thread pair per row; each thread writes its
        // 64-u16 half-row as 8 contiguous short8 stores (128 B total).
        const int b0 = m0 >> 11, t0g = m0 & 2047;
        const int row = tid >> 1;              // n_local
        const int h2  = (n0 + row) >> 6;
        const int c   = (n0 + row) & 63;
        const int tc  = (tid & 1) * 64;        // 64 u16 = 128 B half-row
        u16* dstp = vt + ((size_t)(b0 * HH + h2) * QKD + c) * TT + t0g + tc;
        #pragma unroll
        for (int x = 0; x < 8; x++)
            *(short8*)(dstp + x * 8) = *(const short8*)&smem[row * TSTR + tc + x * 8];
    }
}

// ---------------------------------------------------------------------------
// Output projection GEMM: attn_b[M,K] bf16 @ Wo_t[N,K]^T + bo -> out fp32
// ---------------------------------------------------------------------------
__global__ __launch_bounds__(256) void out_gemm(
    const u16* __restrict__ A, const u16* __restrict__ Bt,
    const float* __restrict__ bo, float* __restrict__ out)
{
    __shared__ u16 As[128 * 64];
    __shared__ u16 Bs[128 * 64];

    const int m0 = blockIdx.y * 128, n0 = blockIdx.x * 128;

    float4v acc[4][4];
    #pragma unroll
    for (int i = 0; i < 4; i++)
        #pragma unroll
        for (int j = 0; j < 4; j++) acc[i][j] = (float4v){0.f, 0.f, 0.f, 0.f};

    gemm_mainloop(A, Bt, m0, n0, As, Bs, acc);

    const int lane = threadIdx.x & 63, wave = threadIdx.x >> 6;
    const int l15 = lane & 15, lg = lane >> 4;
    const int wm = wave >> 1, wn = wave & 1;
    const int mbase = m0 + wm * 64;
    const int nbase = n0 + wn * 64;

    float bov[4];
    #pragma unroll
    for (int nj = 0; nj < 4; nj++) bov[nj] = bo[nbase + nj * 16 + l15];

    #pragma unroll
    for (int mi = 0; mi < 4; mi++)
        #pragma unroll
        for (int r = 0; r < 4; r++) {
            const int m = mbase + mi * 16 + lg * 4 + r;
            float* op = out + (size_t)m * NN + nbase + l15;
            #pragma unroll
            for (int nj = 0; nj < 4; nj++)
                op[nj * 16] = acc[mi][nj][r] + bov[nj];
        }
}

// ---------------------------------------------------------------------------
// MFMA flash attention, causal, PAIRED Q-tiles for uniform work.
// Block = pair (qtL=i, qtH=31-i): exactly 33 stream-iterations each.
// Grid = 16*H*B = 1024 blocks = 4/CU resident, no ragged tail.
// V arrives pre-transposed (B,H,QK,T): both K and V stage with b128s.
// ---------------------------------------------------------------------------
#define LSTR 72

__global__ __launch_bounds__(256, 4) void attn_mfma(
    const u16* __restrict__ qh, const u16* __restrict__ kh,
    const u16* __restrict__ vt, const float* __restrict__ head_scale,
    u16* __restrict__ out)
{
    __shared__ u16 Ks[64 * LSTR];      // K tile [key][d]
    __shared__ u16 Vs[64 * LSTR];      // V^T tile [d][key]
    __shared__ u16 Ps[4][16 * LSTR];   // per-wave P round-trip [q][key]

    const int b = blockIdx.z, h = blockIdx.y, pi = blockIdx.x;
    const int t0L = pi * 64, t0H = (31 - pi) * 64;
    const int tid  = threadIdx.x;
    const int wave = tid >> 6, lane = tid & 63;
    const int l15 = lane & 15, lg = lane >> 4;

    const size_t bh_off = (size_t)(b * HH + h) * TT * QKD;
    const u16* qbh = qh + bh_off;
    const u16* kbh = kh + bh_off;
    const u16* vtb = vt + bh_off;

    short8 qfL[2], qfH[2];
    #pragma unroll
    for (int kc = 0; kc < 2; kc++) {
        qfL[kc] = *(const short8*)(qbh + (size_t)(t0L + wave * 16 + l15) * QKD + kc * 32 + lg * 8);
        qfH[kc] = *(const short8*)(qbh + (size_t)(t0H + wave * 16 + l15) * QKD + kc * 32 + lg * 8);
    }

    float4v oL[4], oH[4];
    #pragma unroll
    for (int nt = 0; nt < 4; nt++) {
        oL[nt] = (float4v){0.f, 0.f, 0.f, 0.f};
        oH[nt] = (float4v){0.f, 0.f, 0.f, 0.f};
    }
    float mL[4] = {-INFINITY, -INFINITY, -INFINITY, -INFINITY};
    float mH[4] = {-INFINITY, -INFINITY, -INFINITY, -INFINITY};
    float lL[4] = {0.f, 0.f, 0.f, 0.f};
    float lH[4] = {0.f, 0.f, 0.f, 0.f};

    u16* pw = Ps[wave];

    auto process = [&](const short8 (&qf)[2], float4v (&o_acc)[4],
                       float (&m_run)[4], float (&l_run)[4], int t0, int j0) {
        float4v sarr[4];
        #pragma unroll
        for (int nt = 0; nt < 4; nt++) {
            float4v s = (float4v){0.f, 0.f, 0.f, 0.f};
            #pragma unroll
            for (int kc = 0; kc < 2; kc++) {
                short8 bfrag = *(const short8*)&Ks[(nt * 16 + l15) * LSTR + kc * 32 + lg * 8];
                s = __builtin_amdgcn_mfma_f32_16x16x32_bf16(qf[kc], bfrag, s, 0, 0, 0);
            }
            sarr[nt] = s;
        }

        if (j0 == t0) {
            const int qbase = t0 + wave * 16 + lg * 4;
            #pragma unroll
            for (int nt = 0; nt < 4; nt++) {
                int jkey = j0 + nt * 16 + l15;
                #pragma unroll
                for (int r = 0; r < 4; r++)
                    if (jkey > qbase + r) sarr[nt][r] = -INFINITY;
            }
        }

        float alpha[4], rowsum[4];
        #pragma unroll
        for (int r = 0; r < 4; r++) {
            float m = fmaxf(fmaxf(sarr[0][r], sarr[1][r]), fmaxf(sarr[2][r], sarr[3][r]));
            m = fmaxf(m, __shfl_xor(m, 1));
            m = fmaxf(m, __shfl_xor(m, 2));
            m = fmaxf(m, __shfl_xor(m, 4));
            m = fmaxf(m, __shfl_xor(m, 8));
            float m_new = fmaxf(m_run[r], m);
            alpha[r] = exp2f(m_run[r] - m_new);
            m_run[r] = m_new;
            rowsum[r] = 0.f;
        }
        #pragma unroll
        for (int nt = 0; nt < 4; nt++) {
            #pragma unroll
            for (int r = 0; r < 4; r++) {
                float p = exp2f(sarr[nt][r] - m_run[r]);
                rowsum[r] += p;
                pw[(lg * 4 + r) * LSTR + nt * 16 + l15] = f2bf(p);
            }
        }
        #pragma unroll
        for (int r = 0; r < 4; r++) {
            float rs = rowsum[r];
            rs += __shfl_xor(rs, 1);
            rs += __shfl_xor(rs, 2);
            rs += __shfl_xor(rs, 4);
            rs += __shfl_xor(rs, 8);
            l_run[r] = l_run[r] * alpha[r] + rs;
        }
        #pragma unroll
        for (int nt = 0; nt < 4; nt++)
            #pragma unroll
            for (int r = 0; r < 4; r++)
                o_acc[nt][r] *= alpha[r];

        short8 pf[2];
        #pragma unroll
        for (int kc = 0; kc < 2; kc++)
            pf[kc] = *(const short8*)&pw[l15 * LSTR + kc * 32 + lg * 8];
        #pragma unroll
        for (int nt = 0; nt < 4; nt++) {
            #pragma unroll
            for (int kc = 0; kc < 2; kc++) {
                short8 vfrag = *(const short8*)&Vs[(nt * 16 + l15) * LSTR + kc * 32 + lg * 8];
                o_acc[nt] = __builtin_amdgcn_mfma_f32_16x16x32_bf16(pf[kc], vfrag, o_acc[nt], 0, 0, 0);
            }
        }
    };

    for (int j0 = 0; j0 <= t0H; j0 += 64) {
        #pragma unroll
        for (int r = 0; r < 2; r++) {
            int idx = r * 256 + tid;
            int row = idx >> 3, cb = (idx & 7) * 8;
            *(short8*)&Ks[row * LSTR + cb] =
                *(const short8*)(kbh + (size_t)(j0 + row) * QKD + cb);
            *(short8*)&Vs[row * LSTR + cb] =
                *(const short8*)(vtb + (size_t)row * TT + j0 + cb);
        }
        __syncthreads();

        process(qfH, oH, mH, lH, t0H, j0);
        if (j0 <= t0L) process(qfL, oL, mL, lL, t0L, j0);
        __syncthreads();
    }

    const float hs = 1.0f + head_scale[h];
    #pragma unroll
    for (int r = 0; r < 4; r++) {
        {
            const int q = t0L + wave * 16 + lg * 4 + r;
            const float f = hs / lL[r];
            u16* op = out + ((size_t)(b * TT + q) * NN) + h * QKD + l15;
            #pragma unroll
            for (int nt = 0; nt < 4; nt++) op[nt * 16] = f2bf(oL[nt][r] * f);
        }
        {
            const int q = t0H + wave * 16 + lg * 4 + r;
            const float f = hs / lH[r];
            u16* op = out + ((size_t)(b * TT + q) * NN) + h * QKD + l15;
            #pragma unroll
            for (int nt = 0; nt < 4; nt++) op[nt * 16] = f2bf(oH[nt][r] * f);
        }
    }
}

// ---------------------------------------------------------------------------
extern "C" void kernel_launch(void* const* d_in, const int* in_sizes, int n_in,
                              void* d_out, int out_size, void* d_ws, size_t ws_size,
                              hipStream_t stream)
{
    const float* q          = (const float*)d_in[0];
    const float* kv         = (const float*)d_in[1];
    /* d_in[2] = causal mask -- handled analytically */
    const int*   qpos       = (const int*)d_in[3];
    const int*   kpos       = (const int*)d_in[4];
    const float* Wq         = (const float*)d_in[5];
    const float* bq         = (const float*)d_in[6];
    const float* Wk         = (const float*)d_in[7];
    const float* bk         = (const float*)d_in[8];
    const float* Wv         = (const float*)d_in[9];
    const float* bv         = (const float*)d_in[10];
    const float* q_scale    = (const float*)d_in[11];
    const float* k_scale    = (const float*)d_in[12];
    const float* head_scale = (const float*)d_in[13];
    const float* Wo         = (const float*)d_in[14];
    const float* bo         = (const float*)d_in[15];
    float* out = (float*)d_out;

    // workspace layout (bytes):
    //   [  0 MB, 16 MB)  qb     (M,K) bf16
    //   [ 16 MB, 32 MB)  kvb    (M,K) bf16
    //   [ 32 MB, 40 MB)  Wt     4 x (N,K) bf16 transposed: Wq,Wk,Wv,Wo
    //   [ 40 MB, 56 MB)  qh_b   (B,H,T,QK) bf16
    //   [ 56 MB, 72 MB)  kh_b   (B,H,T,QK) bf16
    //   [ 72 MB, 88 MB)  vt_b   (B,H,QK,T) bf16  -- V transposed
    //   [ 88 MB,104 MB)  attn_b (B,T,N) bf16
    char* ws = (char*)d_ws;
    u16* qb     = (u16*)(ws);
    u16* kvb    = (u16*)(ws + (16u << 20));
    u16* Wt     = (u16*)(ws + (32u << 20));
    u16* qh_b   = (u16*)(ws + (40u << 20));
    u16* kh_b   = (u16*)(ws + (56u << 20));
    u16* vt_b   = (u16*)(ws + (72u << 20));
    u16* attn_b = (u16*)(ws + (88u << 20));

    acast_kernel<<<dim3(MM * DD / (256 * 4), 2), 256, 0, stream>>>(q, kv, qb, kvb);
    wt_kernel<<<dim3(16, 16, 4), 256, 0, stream>>>(Wq, Wk, Wv, Wo, Wt);
    qkv_gemm<<<dim3(NN / 128, MM / 128, 3), 256, 0, stream>>>(
        qb, kvb, Wt, bq, bk, bv, qpos, kpos, q_scale, k_scale, qh_b, kh_b, vt_b);
    attn_mfma<<<dim3(16, HH, BB), 256, 0, stream>>>(qh_b, kh_b, vt_b, head_scale, attn_b);
    out_gemm<<<dim3(NN / 128, MM / 128), 256, 0, stream>>>(attn_b, Wt + (size_t)3 * KK * NN, bo, out);
}

// Round 7
// 699.451 us; speedup vs baseline: 1.0548x; 1.0112x over previous
//
#include <hip/hip_runtime.h>
#include <math.h>

// Problem constants
#define BB 4
#define TT 2048
#define DD 1024
#define HH 16
#define QKD 64
#define MM (BB*TT)          // 8192
#define NN 1024             // H*QK == D
#define KK 1024

typedef unsigned short u16;
typedef __attribute__((ext_vector_type(8))) short short8;   // 8 bf16 = 4 VGPRs
typedef __attribute__((ext_vector_type(4))) float float4v;  // MFMA C/D

// fp32 -> bf16 round-to-nearest-even
__device__ __forceinline__ u16 f2bf(float f) {
    union { float f; unsigned u; } v; v.f = f;
    unsigned r = (v.u + 0x7FFFu + ((v.u >> 16) & 1u)) >> 16;
    return (u16)r;
}

// async global->LDS, 16B per lane; LDS dest = wave-uniform base + lane*16
typedef __attribute__((address_space(3))) unsigned lds_u32_t;
typedef __attribute__((address_space(1))) const unsigned glb_u32_t;
__device__ __forceinline__ void gl2lds16(const u16* g, u16* l) {
    __builtin_amdgcn_global_load_lds((glb_u32_t*)g, (lds_u32_t*)l, 16, 0, 0);
}

// ---------------------------------------------------------------------------
// fp32 -> bf16 cast for activations (q, kv)
// ---------------------------------------------------------------------------
__global__ __launch_bounds__(256) void acast_kernel(
    const float* __restrict__ a, const float* __restrict__ b,
    u16* __restrict__ da, u16* __restrict__ db)
{
    const float* s = blockIdx.y ? b : a;
    u16* d = blockIdx.y ? db : da;
    size_t i = ((size_t)blockIdx.x * 256 + threadIdx.x) * 4;
    float4 v = *(const float4*)&s[i];
    ushort4 o = { f2bf(v.x), f2bf(v.y), f2bf(v.z), f2bf(v.w) };
    *(ushort4*)&d[i] = o;
}

// ---------------------------------------------------------------------------
// Weight transpose + cast: W[K][N] fp32 -> Wt[N][K] bf16, z selects matrix
// ---------------------------------------------------------------------------
__global__ __launch_bounds__(256) void wt_kernel(
    const float* __restrict__ Wq, const float* __restrict__ Wk,
    const float* __restrict__ Wv, const float* __restrict__ Wo,
    u16* __restrict__ dstbase)
{
    const int z = blockIdx.z;
    const float* src = (z == 0) ? Wq : (z == 1) ? Wk : (z == 2) ? Wv : Wo;
    u16* out = dstbase + (size_t)z * (KK * NN);
    const int bi = blockIdx.y, bj = blockIdx.x;
    __shared__ float tile[64][65];
    const int t = threadIdx.x;
    #pragma unroll
    for (int p = 0; p < 4; p++) {
        int idx = p * 256 + t;
        int r = idx >> 4, c4 = (idx & 15) << 2;
        float4 v = *(const float4*)&src[(size_t)(bi * 64 + r) * NN + bj * 64 + c4];
        tile[r][c4 + 0] = v.x; tile[r][c4 + 1] = v.y;
        tile[r][c4 + 2] = v.z; tile[r][c4 + 3] = v.w;
    }
    __syncthreads();
    #pragma unroll
    for (int p = 0; p < 4; p++) {
        int idx = p * 256 + t;
        int rn = idx >> 4, c4 = (idx & 15) << 2;
        ushort4 o = { f2bf(tile[c4 + 0][rn]), f2bf(tile[c4 + 1][rn]),
                      f2bf(tile[c4 + 2][rn]), f2bf(tile[c4 + 3][rn]) };
        *(ushort4*)&out[(size_t)(bj * 64 + rn) * KK + bi * 64 + c4] = o;
    }
}

// ---------------------------------------------------------------------------
// bf16 MFMA GEMM main loop (m97 structure). See round-3 notes.
// ---------------------------------------------------------------------------
__device__ __forceinline__ void gemm_mainloop(
    const u16* __restrict__ A, const u16* __restrict__ Bt,
    int m0, int n0, u16* As, u16* Bs, float4v (&acc)[4][4])
{
    const int tid = threadIdx.x;
    const int wave = tid >> 6, lane = tid & 63;
    const int l15 = lane & 15, lg = lane >> 4;
    const int wm = wave >> 1, wn = wave & 1;

    const int lr = lane >> 3;
    const int lc = lane & 7;

    for (int k0 = 0; k0 < KK; k0 += 64) {
        #pragma unroll
        for (int i = 0; i < 4; i++) {
            int chunk = wave * 4 + i;
            int row = chunk * 8 + lr;
            int gcb = lc ^ (row & 7);
            gl2lds16(A  + (size_t)(m0 + row) * KK + k0 + gcb * 8, As + chunk * 512);
            gl2lds16(Bt + (size_t)(n0 + row) * KK + k0 + gcb * 8, Bs + chunk * 512);
        }
        __syncthreads();

        short8 af[2][4], bf[2][4];
        #pragma unroll
        for (int kc = 0; kc < 2; kc++) {
            #pragma unroll
            for (int x = 0; x < 4; x++) {
                int ra = wm * 64 + x * 16 + l15;
                int sa = (kc * 4 + lg) ^ (ra & 7);
                af[kc][x] = *(const short8*)(As + ra * 64 + sa * 8);
                int rb = wn * 64 + x * 16 + l15;
                int sb = (kc * 4 + lg) ^ (rb & 7);
                bf[kc][x] = *(const short8*)(Bs + rb * 64 + sb * 8);
            }
        }
        #pragma unroll
        for (int mi = 0; mi < 4; mi++)
            #pragma unroll
            for (int nj = 0; nj < 4; nj++) {
                acc[mi][nj] = __builtin_amdgcn_mfma_f32_16x16x32_bf16(af[0][mi], bf[0][nj], acc[mi][nj], 0, 0, 0);
                acc[mi][nj] = __builtin_amdgcn_mfma_f32_16x16x32_bf16(af[1][mi], bf[1][nj], acc[mi][nj], 0, 0, 0);
            }
        __syncthreads();
    }
}

// ---------------------------------------------------------------------------
// QKV projection GEMM, z in {0:Q, 1:K, 2:V}. Epilogue fuses bias + RMSNorm +
// RoPE (Q,K). ALL outputs -> (B,H,T,QK) bf16 via per-wave LDS bounce so every
// global store is 16 B/lane covering full cache lines (rounds 4-6 showed
// narrow / (B,H,QK,T)-layout stores cost ~1.5 GB of beyond-L2 write traffic).
// ---------------------------------------------------------------------------
#define BSTR 80   // u16 row stride of bounce tile: 16B-aligned, 2-way banks

__global__ __launch_bounds__(256) void qkv_gemm(
    const u16* __restrict__ qb, const u16* __restrict__ kvb,
    const u16* __restrict__ Wt,
    const float* __restrict__ bq, const float* __restrict__ bk, const float* __restrict__ bv,
    const int* __restrict__ qpos, const int* __restrict__ kpos,
    const float* __restrict__ q_scale, const float* __restrict__ k_scale,
    u16* __restrict__ qh, u16* __restrict__ kh, u16* __restrict__ vh)
{
    __shared__ u16 smem[4 * 64 * BSTR];   // 40960 B; mainloop uses first 32 KB
    u16* As = smem;
    u16* Bs = smem + 128 * 64;

    const int z = blockIdx.z;
    const u16* A        = (z == 0) ? qb : kvb;
    const u16* B        = Wt + (size_t)z * (KK * NN);
    const float* bias   = (z == 0) ? bq : (z == 1) ? bk : bv;
    const float* scl    = (z == 0) ? q_scale : k_scale;
    const int* pos_arr  = (z == 0) ? qpos : kpos;

    const int m0 = blockIdx.y * 128, n0 = blockIdx.x * 128;

    float4v acc[4][4];
    #pragma unroll
    for (int i = 0; i < 4; i++)
        #pragma unroll
        for (int j = 0; j < 4; j++) acc[i][j] = (float4v){0.f, 0.f, 0.f, 0.f};

    gemm_mainloop(A, B, m0, n0, As, Bs, acc);
    // mainloop ends with __syncthreads(): smem is free; each wave now uses
    // only its private bounce tile (no further barriers needed).

    const int tid = threadIdx.x;
    const int lane = tid & 63, wave = tid >> 6;
    const int l15 = lane & 15, lg = lane >> 4;
    const int wm = wave >> 1, wn = wave & 1;
    const int h = (n0 >> 6) + wn;          // head for this wave's quadrant
    const int b0 = m0 >> 11;
    const int tq0 = (m0 & 2047) + wm * 64; // t base for this wave

    u16* myT = smem + wave * (64 * BSTR);

    float bia[4];
    #pragma unroll
    for (int nj = 0; nj < 4; nj++)
        bia[nj] = bias[h * 64 + nj * 16 + l15];

    if (z < 2) {
        float sc[4];
        #pragma unroll
        for (int nj = 0; nj < 4; nj++) sc[nj] = 1.0f + scl[nj * 16 + l15];
        float invts[2];
        #pragma unroll
        for (int p = 0; p < 2; p++)
            invts[p] = powf(10000.0f, -(float)(p * 16 + l15) * (1.0f / 32.0f));
        const float QMUL = 0.125f * 1.44269504088896340736f;

        #pragma unroll
        for (int mi = 0; mi < 4; mi++) {
            #pragma unroll
            for (int r = 0; r < 4; r++) {
                const int mrow = mi * 16 + lg * 4 + r;   // local t
                const int t = tq0 + mrow;
                float v[4];
                #pragma unroll
                for (int nj = 0; nj < 4; nj++) v[nj] = acc[mi][nj][r] + bia[nj];

                float ss = v[0]*v[0] + v[1]*v[1] + v[2]*v[2] + v[3]*v[3];
                ss += __shfl_xor(ss, 1);
                ss += __shfl_xor(ss, 2);
                ss += __shfl_xor(ss, 4);
                ss += __shfl_xor(ss, 8);
                float rn = rsqrtf(ss * (1.0f / 64.0f) + 1e-6f);
                #pragma unroll
                for (int nj = 0; nj < 4; nj++) v[nj] = v[nj] * rn * sc[nj];

                const float pos = (float)pos_arr[b0 * TT + t];
                #pragma unroll
                for (int p = 0; p < 2; p++) {
                    float ang = pos * invts[p];
                    float s = sinf(ang), c = cosf(ang);
                    float x1 = v[p], x2 = v[p + 2];
                    v[p]     = x1 * c - x2 * s;
                    v[p + 2] = x2 * c + x1 * s;
                }
                if (z == 0) {
                    #pragma unroll
                    for (int nj = 0; nj < 4; nj++) v[nj] *= QMUL;
                }
                #pragma unroll
                for (int nj = 0; nj < 4; nj++)
                    myT[mrow * BSTR + nj * 16 + l15] = f2bf(v[nj]);
            }
        }
    } else {
        // V: bias only
        #pragma unroll
        for (int mi = 0; mi < 4; mi++)
            #pragma unroll
            for (int r = 0; r < 4; r++) {
                const int mrow = mi * 16 + lg * 4 + r;
                #pragma unroll
                for (int nj = 0; nj < 4; nj++)
                    myT[mrow * BSTR + nj * 16 + l15] = f2bf(acc[mi][nj][r] + bia[nj]);
            }
    }

    // wide writeback: lane -> (row = x*8 + lane>>3, 16B chunk = lane&7).
    // every store instruction covers 8 rows x 128 B fully -> whole lines.
    u16* dstb = (z == 0) ? qh : (z == 1) ? kh : vh;
    const int lrow = lane >> 3, lchk = lane & 7;
    u16* dst0 = dstb + ((size_t)(b0 * HH + h) * TT + tq0 + lrow) * QKD + lchk * 8;
    const u16* src0 = myT + lrow * BSTR + lchk * 8;
    #pragma unroll
    for (int x = 0; x < 8; x++)
        *(short8*)(dst0 + (size_t)x * 8 * QKD) = *(const short8*)(src0 + x * 8 * BSTR);
}

// ---------------------------------------------------------------------------
// Output projection GEMM: attn_b[M,K] bf16 @ Wo_t[N,K]^T + bo -> out fp32
// ---------------------------------------------------------------------------
__global__ __launch_bounds__(256) void out_gemm(
    const u16* __restrict__ A, const u16* __restrict__ Bt,
    const float* __restrict__ bo, float* __restrict__ out)
{
    __shared__ u16 As[128 * 64];
    __shared__ u16 Bs[128 * 64];

    const int m0 = blockIdx.y * 128, n0 = blockIdx.x * 128;

    float4v acc[4][4];
    #pragma unroll
    for (int i = 0; i < 4; i++)
        #pragma unroll
        for (int j = 0; j < 4; j++) acc[i][j] = (float4v){0.f, 0.f, 0.f, 0.f};

    gemm_mainloop(A, Bt, m0, n0, As, Bs, acc);

    const int lane = threadIdx.x & 63, wave = threadIdx.x >> 6;
    const int l15 = lane & 15, lg = lane >> 4;
    const int wm = wave >> 1, wn = wave & 1;
    const int mbase = m0 + wm * 64;
    const int nbase = n0 + wn * 64;

    float bov[4];
    #pragma unroll
    for (int nj = 0; nj < 4; nj++) bov[nj] = bo[nbase + nj * 16 + l15];

    #pragma unroll
    for (int mi = 0; mi < 4; mi++)
        #pragma unroll
        for (int r = 0; r < 4; r++) {
            const int m = mbase + mi * 16 + lg * 4 + r;
            float* op = out + (size_t)m * NN + nbase + l15;
            #pragma unroll
            for (int nj = 0; nj < 4; nj++)
                op[nj * 16] = acc[mi][nj][r] + bov[nj];
        }
}

// ---------------------------------------------------------------------------
// MFMA flash attention, causal, PAIRED Q-tiles for uniform work.
// Block = pair (qtL=i, qtH=31-i): exactly 33 stream-iterations each.
// Grid = 16*H*B = 1024 blocks = 4/CU resident, no ragged tail.
// V is (B,H,T,QK); transposed per-tile into LDS (scalar writes, LDS is cheap).
// ---------------------------------------------------------------------------
#define LSTR 72

__global__ __launch_bounds__(256, 4) void attn_mfma(
    const u16* __restrict__ qh, const u16* __restrict__ kh,
    const u16* __restrict__ vh, const float* __restrict__ head_scale,
    u16* __restrict__ out)
{
    __shared__ u16 Ks[64 * LSTR];      // K tile [key][d]
    __shared__ u16 Vs[64 * LSTR];      // V tile transposed [d][key]
    __shared__ u16 Ps[4][16 * LSTR];   // per-wave P round-trip [q][key]

    const int b = blockIdx.z, h = blockIdx.y, pi = blockIdx.x;
    const int t0L = pi * 64, t0H = (31 - pi) * 64;
    const int tid  = threadIdx.x;
    const int wave = tid >> 6, lane = tid & 63;
    const int l15 = lane & 15, lg = lane >> 4;

    const size_t bh_off = (size_t)(b * HH + h) * TT * QKD;
    const u16* qbh = qh + bh_off;
    const u16* kbh = kh + bh_off;
    const u16* vbh = vh + bh_off;

    short8 qfL[2], qfH[2];
    #pragma unroll
    for (int kc = 0; kc < 2; kc++) {
        qfL[kc] = *(const short8*)(qbh + (size_t)(t0L + wave * 16 + l15) * QKD + kc * 32 + lg * 8);
        qfH[kc] = *(const short8*)(qbh + (size_t)(t0H + wave * 16 + l15) * QKD + kc * 32 + lg * 8);
    }

    float4v oL[4], oH[4];
    #pragma unroll
    for (int nt = 0; nt < 4; nt++) {
        oL[nt] = (float4v){0.f, 0.f, 0.f, 0.f};
        oH[nt] = (float4v){0.f, 0.f, 0.f, 0.f};
    }
    float mL[4] = {-INFINITY, -INFINITY, -INFINITY, -INFINITY};
    float mH[4] = {-INFINITY, -INFINITY, -INFINITY, -INFINITY};
    float lL[4] = {0.f, 0.f, 0.f, 0.f};
    float lH[4] = {0.f, 0.f, 0.f, 0.f};

    u16* pw = Ps[wave];

    auto process = [&](const short8 (&qf)[2], float4v (&o_acc)[4],
                       float (&m_run)[4], float (&l_run)[4], int t0, int j0) {
        float4v sarr[4];
        #pragma unroll
        for (int nt = 0; nt < 4; nt++) {
            float4v s = (float4v){0.f, 0.f, 0.f, 0.f};
            #pragma unroll
            for (int kc = 0; kc < 2; kc++) {
                short8 bfrag = *(const short8*)&Ks[(nt * 16 + l15) * LSTR + kc * 32 + lg * 8];
                s = __builtin_amdgcn_mfma_f32_16x16x32_bf16(qf[kc], bfrag, s, 0, 0, 0);
            }
            sarr[nt] = s;
        }

        if (j0 == t0) {
            const int qbase = t0 + wave * 16 + lg * 4;
            #pragma unroll
            for (int nt = 0; nt < 4; nt++) {
                int jkey = j0 + nt * 16 + l15;
                #pragma unroll
                for (int r = 0; r < 4; r++)
                    if (jkey > qbase + r) sarr[nt][r] = -INFINITY;
            }
        }

        float alpha[4], rowsum[4];
        #pragma unroll
        for (int r = 0; r < 4; r++) {
            float m = fmaxf(fmaxf(sarr[0][r], sarr[1][r]), fmaxf(sarr[2][r], sarr[3][r]));
            m = fmaxf(m, __shfl_xor(m, 1));
            m = fmaxf(m, __shfl_xor(m, 2));
            m = fmaxf(m, __shfl_xor(m, 4));
            m = fmaxf(m, __shfl_xor(m, 8));
            float m_new = fmaxf(m_run[r], m);
            alpha[r] = exp2f(m_run[r] - m_new);
            m_run[r] = m_new;
            rowsum[r] = 0.f;
        }
        #pragma unroll
        for (int nt = 0; nt < 4; nt++) {
            #pragma unroll
            for (int r = 0; r < 4; r++) {
                float p = exp2f(sarr[nt][r] - m_run[r]);
                rowsum[r] += p;
                pw[(lg * 4 + r) * LSTR + nt * 16 + l15] = f2bf(p);
            }
        }
        #pragma unroll
        for (int r = 0; r < 4; r++) {
            float rs = rowsum[r];
            rs += __shfl_xor(rs, 1);
            rs += __shfl_xor(rs, 2);
            rs += __shfl_xor(rs, 4);
            rs += __shfl_xor(rs, 8);
            l_run[r] = l_run[r] * alpha[r] + rs;
        }
        #pragma unroll
        for (int nt = 0; nt < 4; nt++)
            #pragma unroll
            for (int r = 0; r < 4; r++)
                o_acc[nt][r] *= alpha[r];

        short8 pf[2];
        #pragma unroll
        for (int kc = 0; kc < 2; kc++)
            pf[kc] = *(const short8*)&pw[l15 * LSTR + kc * 32 + lg * 8];
        #pragma unroll
        for (int nt = 0; nt < 4; nt++) {
            #pragma unroll
            for (int kc = 0; kc < 2; kc++) {
                short8 vfrag = *(const short8*)&Vs[(nt * 16 + l15) * LSTR + kc * 32 + lg * 8];
                o_acc[nt] = __builtin_amdgcn_mfma_f32_16x16x32_bf16(pf[kc], vfrag, o_acc[nt], 0, 0, 0);
            }
        }
    };

    for (int j0 = 0; j0 <= t0H; j0 += 64) {
        // stage K [key][d] (vectorized) and V transposed [d][key] (scalar LDS)
        #pragma unroll
        for (int r = 0; r < 2; r++) {
            int idx = r * 256 + tid;
            int row = idx >> 3, cb = (idx & 7) * 8;
            *(short8*)&Ks[row * LSTR + cb] =
                *(const short8*)(kbh + (size_t)(j0 + row) * QKD + cb);

            int j   = tid & 63;
            int dv0 = (tid >> 6) * 8 + r * 32;
            short8 v8 = *(const short8*)(vbh + (size_t)(j0 + j) * QKD + dv0);
            #pragma unroll
            for (int i = 0; i < 8; i++)
                Vs[(dv0 + i) * LSTR + j] = (u16)v8[i];
        }
        __syncthreads();

        process(qfH, oH, mH, lH, t0H, j0);
        if (j0 <= t0L) process(qfL, oL, mL, lL, t0L, j0);
        __syncthreads();
    }

    const float hs = 1.0f + head_scale[h];
    #pragma unroll
    for (int r = 0; r < 4; r++) {
        {
            const int q = t0L + wave * 16 + lg * 4 + r;
            const float f = hs / lL[r];
            u16* op = out + ((size_t)(b * TT + q) * NN) + h * QKD + l15;
            #pragma unroll
            for (int nt = 0; nt < 4; nt++) op[nt * 16] = f2bf(oL[nt][r] * f);
        }
        {
            const int q = t0H + wave * 16 + lg * 4 + r;
            const float f = hs / lH[r];
            u16* op = out + ((size_t)(b * TT + q) * NN) + h * QKD + l15;
            #pragma unroll
            for (int nt = 0; nt < 4; nt++) op[nt * 16] = f2bf(oH[nt][r] * f);
        }
    }
}

// ---------------------------------------------------------------------------
extern "C" void kernel_launch(void* const* d_in, const int* in_sizes, int n_in,
                              void* d_out, int out_size, void* d_ws, size_t ws_size,
                              hipStream_t stream)
{
    const float* q          = (const float*)d_in[0];
    const float* kv         = (const float*)d_in[1];
    /* d_in[2] = causal mask -- handled analytically */
    const int*   qpos       = (const int*)d_in[3];
    const int*   kpos       = (const int*)d_in[4];
    const float* Wq         = (const float*)d_in[5];
    const float* bq         = (const float*)d_in[6];
    const float* Wk         = (const float*)d_in[7];
    const float* bk         = (const float*)d_in[8];
    const float* Wv         = (const float*)d_in[9];
    const float* bv         = (const float*)d_in[10];
    const float* q_scale    = (const float*)d_in[11];
    const float* k_scale    = (const float*)d_in[12];
    const float* head_scale = (const float*)d_in[13];
    const float* Wo         = (const float*)d_in[14];
    const float* bo         = (const float*)d_in[15];
    float* out = (float*)d_out;

    // workspace layout (bytes):
    //   [  0 MB, 16 MB)  qb     (M,K) bf16
    //   [ 16 MB, 32 MB)  kvb    (M,K) bf16
    //   [ 32 MB, 40 MB)  Wt     4 x (N,K) bf16 transposed: Wq,Wk,Wv,Wo
    //   [ 40 MB, 56 MB)  qh_b   (B,H,T,QK) bf16
    //   [ 56 MB, 72 MB)  kh_b   (B,H,T,QK) bf16
    //   [ 72 MB, 88 MB)  vh_b   (B,H,T,QK) bf16
    //   [ 88 MB,104 MB)  attn_b (B,T,N) bf16
    char* ws = (char*)d_ws;
    u16* qb     = (u16*)(ws);
    u16* kvb    = (u16*)(ws + (16u << 20));
    u16* Wt     = (u16*)(ws + (32u << 20));
    u16* qh_b   = (u16*)(ws + (40u << 20));
    u16* kh_b   = (u16*)(ws + (56u << 20));
    u16* vh_b   = (u16*)(ws + (72u << 20));
    u16* attn_b = (u16*)(ws + (88u << 20));

    acast_kernel<<<dim3(MM * DD / (256 * 4), 2), 256, 0, stream>>>(q, kv, qb, kvb);
    wt_kernel<<<dim3(16, 16, 4), 256, 0, stream>>>(Wq, Wk, Wv, Wo, Wt);
    qkv_gemm<<<dim3(NN / 128, MM / 128, 3), 256, 0, stream>>>(
        qb, kvb, Wt, bq, bk, bv, qpos, kpos, q_scale, k_scale, qh_b, kh_b, vh_b);
    attn_mfma<<<dim3(16, HH, BB), 256, 0, stream>>>(qh_b, kh_b, vh_b, head_scale, attn_b);
    out_gemm<<<dim3(NN / 128, MM / 128), 256, 0, stream>>>(attn_b, Wt + (size_t)3 * KK * NN, bo, out);
}